// Round 9
// baseline (3948.924 us; speedup 1.0000x reference)
//
#include <hip/hip_runtime.h>
#include <hip/hip_fp16.h>

#define GD 256   // 1 WG per CU, persistent
#define BD 1024  // 16 waves

constexpr int TSTEPS = 256;
constexpr int DD = 512;
constexpr int LC = 128;

// ---- ws float offsets ----
constexpr size_t OFF_FLAGS_F = 0;       // grid flags: 256 lines (stride 32 ints)
constexpr size_t OFF_REL_F   = 8192;    // 8 release lines
constexpr size_t OFF_GFLG_F  = 8448;    // group flags [32 b][8 oct][32 ints]
constexpr size_t OFF_SCP     = 16640;   // [32 b][8 oct][128 l] f32 score partials
constexpr size_t OFF_H16_F   = 49408;   // h16 base
// ---- h16-unit offsets ----
constexpr size_t HO_HX    = 0;          // [32 b][512] h (latest only)
constexpr size_t HO_ATT   = 16384;      // [4096 r][512] attc
constexpr size_t HO_U16   = 2113536;    // [8 oct][256 kp][256 cc] h2
constexpr size_t HO_WH16  = 3162112;    // [8 octa][256 kp][64 a] h2
constexpr size_t HO_CTXV  = 3424256;    // [32 b][8 oct][128 l][256 cc]
constexpr size_t HO_XW    = 11812864;   // [32 b][8 oct][256 st][256 cc]

typedef _Float16 h16;
typedef _Float16 h2  __attribute__((ext_vector_type(2)));
typedef _Float16 h8v __attribute__((ext_vector_type(8)));
union H8  { h8v v; h2 p[4]; };
union H2U { h2 h; unsigned u; };
union HSU { h16 h; unsigned short u; };

__device__ __forceinline__ float rcp_fast(float x) { return __builtin_amdgcn_rcpf(x); }
__device__ __forceinline__ float ftanh(float x) {
  float e = __expf(2.0f * x);
  return 1.0f - 2.0f * rcp_fast(e + 1.0f);
}
__device__ __forceinline__ float fsig(float x) { return rcp_fast(1.0f + __expf(-x)); }
__device__ __forceinline__ float fdot2(h2 a, h2 b, float c) {
  return __builtin_amdgcn_fdot2(a, b, c, false);
}

__device__ __forceinline__ float cloadf(const float* p) {
  return __hip_atomic_load(p, __ATOMIC_RELAXED, __HIP_MEMORY_SCOPE_AGENT);
}
__device__ __forceinline__ unsigned cloadu(const unsigned* p) {
  return __hip_atomic_load(p, __ATOMIC_RELAXED, __HIP_MEMORY_SCOPE_AGENT);
}
__device__ __forceinline__ void cstoref(float* p, float v) {
  __hip_atomic_store(p, v, __ATOMIC_RELAXED, __HIP_MEMORY_SCOPE_AGENT);
}
__device__ __forceinline__ void cstoreu(unsigned* p, unsigned v) {
  __hip_atomic_store(p, v, __ATOMIC_RELAXED, __HIP_MEMORY_SCOPE_AGENT);
}
__device__ __forceinline__ void cstoreu8(unsigned long long* p, unsigned long long v) {
  __hip_atomic_store(p, v, __ATOMIC_RELAXED, __HIP_MEMORY_SCOPE_AGENT);
}
__device__ __forceinline__ void cstores(h16* p, h16 v) {
  HSU s; s.h = v;
  __hip_atomic_store((unsigned short*)p, s.u, __ATOMIC_RELAXED,
                     __HIP_MEMORY_SCOPE_AGENT);
}

// grid barrier (setup only)
__device__ __forceinline__ void gsync(int* flags, int* rel, int w, int& gen) {
  __syncthreads();
  gen++;
  const int t = threadIdx.x;
  if (w == 0) {
    if (t < 64) {
      if (t == 0)
        __hip_atomic_store(flags, gen, __ATOMIC_RELAXED, __HIP_MEMORY_SCOPE_AGENT);
      for (;;) {
        int m = gen;
#pragma unroll
        for (int i = 0; i < 4; i++) {
          int v = __hip_atomic_load(flags + (t + i * 64) * 32,
                                    __ATOMIC_RELAXED, __HIP_MEMORY_SCOPE_AGENT);
          m = (v < m) ? v : m;
        }
        if (__all(m >= gen)) break;
      }
      if (t == 0) {
#pragma unroll
        for (int i = 0; i < 8; i++)
          __hip_atomic_store(rel + i * 32, gen, __ATOMIC_RELAXED,
                             __HIP_MEMORY_SCOPE_AGENT);
      }
    }
    asm volatile("" ::: "memory");
  } else {
    if (t == 0) {
      __hip_atomic_store(flags + w * 32, gen, __ATOMIC_RELAXED,
                         __HIP_MEMORY_SCOPE_AGENT);
      const int* r = rel + (w & 7) * 32;
      while (__hip_atomic_load(r, __ATOMIC_RELAXED, __HIP_MEMORY_SCOPE_AGENT) < gen)
        __builtin_amdgcn_s_sleep(1);
    }
    asm volatile("" ::: "memory");
  }
  __syncthreads();
}

// 8-WG (per-batch) group barrier: symmetric flag + poll
__device__ __forceinline__ void gbar8(int* gf, int oct, int& sg) {
  __syncthreads();
  sg++;
  const int t = threadIdx.x;
  if (t < 64) {
    if (t == 0)
      __hip_atomic_store(gf + oct * 32, sg, __ATOMIC_RELAXED,
                         __HIP_MEMORY_SCOPE_AGENT);
    for (;;) {
      int v = sg;
      if (t < 8)
        v = __hip_atomic_load(gf + t * 32, __ATOMIC_RELAXED,
                              __HIP_MEMORY_SCOPE_AGENT);
      if (__all(v >= sg)) break;
      __builtin_amdgcn_s_sleep(1);
    }
  }
  asm volatile("" ::: "memory");
  __syncthreads();
}

__global__ __launch_bounds__(BD, 4) void attn_lstm_persistent(
    const float* __restrict__ x, const float* __restrict__ ctx,
    const float* __restrict__ W, const float* __restrict__ V,
    const float* __restrict__ U, const float* __restrict__ bias,
    const float* __restrict__ Wh, const float* __restrict__ Wc,
    const float* __restrict__ batt, const float* __restrict__ wprj,
    float* __restrict__ out, float* __restrict__ ws) {
  __shared__ __align__(16) unsigned char smem[46848];
  h16*   attcL = (h16*)smem;                   // [128 l][66] = 16896 B
  float* red   = (float*)(smem + 16896);       // 4096 f (P1: [4][256]; P2: [16][256])
  float* red2  = (float*)(smem + 33280);       // [16][64] f
  h2*    hLDS  = (h2*)(smem + 37376);          // 256 h2 = h[b]
  float* hUk   = (float*)(smem + 38400);       // 256
  float* spp   = (float*)(smem + 39424);       // 1024 (score-partial gather)
  float* sl    = (float*)(smem + 43520);       // 128 (exp scores)
  h2*    anL   = (h2*)(smem + 44032);          // 64 (fp16 alpha pairs)
  float* hattL = (float*)(smem + 44288);       // 64
  float* wpL   = (float*)(smem + 44544);       // 64
  float* biasS = (float*)(smem + 44800);       // 256
  float* pre   = (float*)(smem + 45824);       // 256

  const int w = blockIdx.x;
  const int t = threadIdx.x;
  const int b = w >> 3;    // batch owned by this group
  const int oct = w & 7;   // dim-slice [64*oct, 64*oct+64)

  int* flags = (int*)(ws + OFF_FLAGS_F);
  int* rel   = (int*)(ws + OFF_REL_F);
  int* gfl   = (int*)(ws + OFF_GFLG_F) + b * 256;
  float* scP = ws + OFF_SCP;
  h16* hb16  = (h16*)(ws + OFF_H16_F);
  h16* hX    = hb16 + HO_HX;
  h16* att16 = hb16 + HO_ATT;
  h16* ctxVp = hb16 + HO_CTXV;
  h16* xw16  = hb16 + HO_XW;

  int gen = 0, sg = 0;
  float c_reg = 0.f;       // t<64: cell state c[b][64*oct + t]
  float hn_prev = 0.f;     // t<64: h of previous step (deferred out-store)

  // ================= setup (verified packing, kept identical) =================
  {
    const int kp = w;
    {
      const float* r0p = U + (size_t)(2 * kp) * 2048;
      const float* r1p = r0p + 2048;
      const int col0 = 2 * t;
      float u00 = r0p[col0], u01 = r0p[col0 + 1];
      float u10 = r1p[col0], u11 = r1p[col0 + 1];
      int oc  = (col0 & 511) >> 6;
      int cc0 = ((col0 >> 9) << 6) | (col0 & 63);
      H2U p0; p0.h = h2{(h16)u00, (h16)u10};
      H2U p1; p1.h = h2{(h16)u01, (h16)u11};
      unsigned long long pk =
          (unsigned long long)p0.u | ((unsigned long long)p1.u << 32);
      cstoreu8((unsigned long long*)((h2*)(hb16 + HO_U16) +
                                     (size_t)oc * 65536 + (size_t)kp * 256 + cc0),
               pk);
    }
    if (t < 512) {
      float w0 = Wh[(size_t)(2 * kp) * DD + t];
      float w1 = Wh[(size_t)(2 * kp + 1) * DD + t];
      H2U pu; pu.h = h2{(h16)w0, (h16)w1};
      cstoreu((unsigned*)((h2*)(hb16 + HO_WH16) + (size_t)(t >> 6) * 16384 +
                          (size_t)kp * 64 + (t & 63)),
              pu.u);
    }
  }
  // attc16 = fp16(ctx @ Wc + b_att): 16 rows per WG
  {
    float* fbuf = (float*)smem;  // 32 KB staging (dead after gsync)
    const int r0 = w * 16;
#pragma unroll
    for (int i = 0; i < 2; i++) {
      int idx4 = i * BD + t;
      int row = idx4 >> 7, c4 = idx4 & 127;
      ((float4*)fbuf)[idx4] = ((const float4*)(ctx + (size_t)(r0 + row) * DD))[c4];
    }
    __syncthreads();
    const int a0 = t & 511, rh = t >> 9;
    float acc[8];
#pragma unroll
    for (int r = 0; r < 8; r++) acc[r] = 0.f;
    for (int cc = 0; cc < DD; cc++) {
      float wv = Wc[(size_t)cc * DD + a0];
#pragma unroll
      for (int r = 0; r < 8; r++)
        acc[r] += fbuf[(8 * rh + r) * DD + cc] * wv;
    }
    const float ba = batt[a0];
    for (int r = 0; r < 8; r++)
      cstores(att16 + (size_t)(r0 + 8 * rh + r) * DD + a0, (h16)(acc[r] + ba));
    __syncthreads();
  }
  // xw16 / ctxVp produced with setup-role (bS = w>>3, octS = w&7) — == (b, oct)
  {
    const int bS = w >> 3, octS = w & 7;
    h2* xstage = (h2*)smem;  // [32][256]
    for (int chk = 0; chk < 8; chk++) {
      const int st0 = chk * 32;
      {
        const int row = t >> 5, seg = t & 31;
        const float* src = x + ((size_t)bS * TSTEPS + st0 + row) * DD + seg * 16;
        h2* dst = xstage + row * 256 + seg * 8;
#pragma unroll
        for (int q = 0; q < 4; q++) {
          float4 v = *(const float4*)(src + 4 * q);
          dst[2 * q]     = h2{(h16)v.x, (h16)v.y};
          dst[2 * q + 1] = h2{(h16)v.z, (h16)v.w};
        }
      }
      __syncthreads();
      const int cc = t & 255, sq = t >> 8;
      const int col = ((cc >> 6) << 9) + 64 * octS + (cc & 63);
      float acc[8];
#pragma unroll
      for (int jj = 0; jj < 8; jj++) acc[jj] = 0.f;
#pragma unroll 2
      for (int kp = 0; kp < 256; kp++) {
        float w0 = W[(size_t)(2 * kp) * 2048 + col];
        float w1 = W[(size_t)(2 * kp + 1) * 2048 + col];
        h2 wp = h2{(h16)w0, (h16)w1};
#pragma unroll
        for (int jj = 0; jj < 8; jj++)
          acc[jj] = fdot2(xstage[(sq * 8 + jj) * 256 + kp], wp, acc[jj]);
      }
#pragma unroll
      for (int jj = 0; jj < 8; jj++)
        cstores(xw16 + (((size_t)(bS * 8 + octS) * 256) + st0 + sq * 8 + jj) * 256 + cc,
                (h16)acc[jj]);
      __syncthreads();
    }
    for (int chk = 0; chk < 4; chk++) {
      const int l0 = chk * 32;
      {
        const int row = t >> 5, seg = t & 31;
        const float* src = ctx + ((size_t)bS * LC + l0 + row) * DD + seg * 16;
        h2* dst = xstage + row * 256 + seg * 8;
#pragma unroll
        for (int q = 0; q < 4; q++) {
          float4 v = *(const float4*)(src + 4 * q);
          dst[2 * q]     = h2{(h16)v.x, (h16)v.y};
          dst[2 * q + 1] = h2{(h16)v.z, (h16)v.w};
        }
      }
      __syncthreads();
      const int cc = t & 255, lq = t >> 8;
      const int col = ((cc >> 6) << 9) + 64 * octS + (cc & 63);
      float acc[8];
#pragma unroll
      for (int jj = 0; jj < 8; jj++) acc[jj] = 0.f;
#pragma unroll 2
      for (int kp = 0; kp < 256; kp++) {
        float v0 = V[(size_t)(2 * kp) * 2048 + col];
        float v1 = V[(size_t)(2 * kp + 1) * 2048 + col];
        h2 vp = h2{(h16)v0, (h16)v1};
#pragma unroll
        for (int jj = 0; jj < 8; jj++)
          acc[jj] = fdot2(xstage[(lq * 8 + jj) * 256 + kp], vp, acc[jj]);
      }
#pragma unroll
      for (int jj = 0; jj < 8; jj++)
        cstores(ctxVp + (((size_t)(bS * 8 + octS) * 128) + l0 + lq * 8 + jj) * 256 + cc,
                (h16)acc[jj]);
      __syncthreads();
    }
  }
  gsync(flags, rel, w, gen);

  // ======== persistent operands: U -> 64 VGPR, ctxV -> 16 VGPR, attc -> LDS ====
  const int ccT = t & 255, kq = t >> 8;  // hU: packed col ccT, kp in [64kq, 64kq+64)
  h2 u[64], cvp01[8], cvp23[8];
  {
    const h2* Ub = (const h2*)(hb16 + HO_U16) + (size_t)oct * 65536 + ccT;
#pragma unroll
    for (int i = 0; i < 64; i++) u[i] = Ub[(size_t)(64 * kq + i) * 256];
  }
  {
    const int ccg = t & 31, lq = t >> 5;
    const h16* cvb = ctxVp + ((size_t)(b * 8 + oct) * 128) * 256 + ccg * 8;
    H8 p0, p1, p2, p3;
    p0.v = *(const h8v*)(cvb + (size_t)(4 * lq + 0) * 256);
    p1.v = *(const h8v*)(cvb + (size_t)(4 * lq + 1) * 256);
    p2.v = *(const h8v*)(cvb + (size_t)(4 * lq + 2) * 256);
    p3.v = *(const h8v*)(cvb + (size_t)(4 * lq + 3) * 256);
#pragma unroll
    for (int j8 = 0; j8 < 8; j8++) {
      cvp01[j8] = h2{p0.v[j8], p1.v[j8]};
      cvp23[j8] = h2{p2.v[j8], p3.v[j8]};
    }
  }
  {
    // attcL[l][66]: my batch's 64 a-cols (a = 64*oct + [0,64))
    const int l = t >> 3, as = t & 7;
    uint4 v = *(const uint4*)(att16 + (size_t)(b * LC + l) * DD + 64 * oct + 8 * as);
    unsigned* dp = (unsigned*)(attcL + l * 66 + 8 * as);
    dp[0] = v.x; dp[1] = v.y; dp[2] = v.z; dp[3] = v.w;
  }
  if (t < 64) wpL[t] = wprj[64 * oct + t];
  if (t < 256) biasS[t] = bias[(size_t)(t >> 6) * 512 + 64 * oct + (t & 63)];
  __syncthreads();

  const h2* WhB = (const h2*)(hb16 + HO_WH16) + (size_t)oct * 16384;

  // ========== recurrence: 2 phases, 2 group barriers/step ==========
  for (int step = 0; step < TSTEPS; step++) {
    float xwv = 0.f;

    // deferred out-store for previous step (ack drains under P1 compute)
    if (t < 64 && step > 0)
      out[((size_t)b * TSTEPS + step - 1) * DD + 64 * oct + t] = hn_prev;

    // ---- P1: h gather; hU (U regs, local); hatt (Wh L2); scores (local) ----
    {
      if (t < 256) {
        unsigned hv = 0;
        if (step > 0) hv = cloadu((const unsigned*)(hX + (size_t)b * DD + 2 * t));
        ((unsigned*)hLDS)[t] = hv;
      }
      __syncthreads();
      // hU partial: 64 fdot2, register U
      {
        float f0 = 0.f, f1 = 0.f;
        const int base = 64 * kq;
#pragma unroll
        for (int i = 0; i < 32; i++) f0 = fdot2(hLDS[base + i], u[i], f0);
#pragma unroll
        for (int i = 32; i < 64; i++) f1 = fdot2(hLDS[base + i], u[i], f1);
        red[kq * 256 + ccT] = f0 + f1;
      }
      // hatt partial: 16 fdot2, Wh streamed (64 KB, L2-resident, write-once)
      {
        const int aL = t & 63, ks = t >> 6;
        float g0 = 0.f;
#pragma unroll
        for (int i = 0; i < 16; i++)
          g0 = fdot2(hLDS[16 * ks + i], WhB[(size_t)(16 * ks + i) * 64 + aL], g0);
        red2[ks * 64 + aL] = g0;
      }
      // xw prefetch for this step (hides HBM latency under P1)
      if (t < 256)
        xwv = (float)xw16[(((size_t)(b * 8 + oct)) * 256 + step) * 256 + t];
      __syncthreads();
      if (t < 256) {
        hUk[t] = red[t] + red[256 + t] + red[512 + t] + red[768 + t];
      } else if (t < 320) {
        const int a = t - 256;
        float s = 0.f;
#pragma unroll
        for (int k = 0; k < 16; k++) s += red2[k * 64 + a];
        hattL[a] = s;
      }
      __syncthreads();
      // score partials over my 64 a-cols, all 128 l
      {
        const int l = t >> 3, as = t & 7;
        const h16* arow = attcL + l * 66 + 8 * as;
        float p = 0.f;
#pragma unroll
        for (int aa = 0; aa < 8; aa++)
          p += ftanh((float)arow[aa] + hattL[8 * as + aa]) * wpL[8 * as + aa];
        p += __shfl_xor(p, 1); p += __shfl_xor(p, 2); p += __shfl_xor(p, 4);
        if (as == 0)
          cstoref(scP + (size_t)b * 1024 + oct * 128 + l, p);
      }
    }
    gbar8(gfl, oct, sg);

    // ---- P2: sum 8 partials -> softmax (1 wave) -> PV (regs) -> gates -> h ----
    {
      spp[t] = cloadf(scP + (size_t)b * 1024 + t);  // [oct'=t>>7][l=t&127]
      __syncthreads();
      if (t < 64) {
        float s0 = 0.f, s1 = 0.f;
#pragma unroll
        for (int o = 0; o < 8; o++) {
          s0 += spp[o * 128 + t];
          s1 += spp[o * 128 + 64 + t];
        }
        float e0 = __expf(s0), e1 = __expf(s1);
        sl[t] = e0; sl[64 + t] = e1;
        float z = e0 + e1;
        z += __shfl_xor(z, 32); z += __shfl_xor(z, 16); z += __shfl_xor(z, 8);
        z += __shfl_xor(z, 4);  z += __shfl_xor(z, 2);  z += __shfl_xor(z, 1);
        float zi = rcp_fast(z);
        anL[t] = h2{(h16)(sl[2 * t] * zi), (h16)(sl[2 * t + 1] * zi)};
      }
      __syncthreads();
      {
        const int ccg = t & 31, lq = t >> 5, w16 = t >> 6;
        h2 a01 = anL[2 * lq], a23 = anL[2 * lq + 1];
        float acc8[8];
#pragma unroll
        for (int j8 = 0; j8 < 8; j8++)
          acc8[j8] = fdot2(a23, cvp23[j8], fdot2(a01, cvp01[j8], 0.f));
#pragma unroll
        for (int j8 = 0; j8 < 8; j8++) acc8[j8] += __shfl_xor(acc8[j8], 32);
        if ((t & 63) < 32) {
#pragma unroll
          for (int j8 = 0; j8 < 8; j8++)
            red[w16 * 256 + ccg * 8 + j8] = acc8[j8];
        }
      }
      __syncthreads();
      if (t < 256) {
        float pvs = 0.f;
#pragma unroll
        for (int k = 0; k < 16; k++) pvs += red[k * 256 + t];
        pre[t] = pvs + hUk[t] + xwv + biasS[t];  // pvs already normalized
      }
      __syncthreads();
      if (t < 64) {
        const int d = t;
        float pi = pre[d], pf = pre[64 + d], po = pre[128 + d], pg = pre[192 + d];
        float ig = fsig(pi), fg = fsig(pf), og = fsig(po), gg = ftanh(pg);
        float cn = fg * c_reg + ig * gg;
        c_reg = cn;
        float hn = og * ftanh(cn);
        hn_prev = hn;
        cstores(hX + (size_t)b * DD + 64 * oct + d, (h16)hn);
      }
    }
    gbar8(gfl, oct, sg);
  }
  // final out-store (step TSTEPS-1)
  if (t < 64)
    out[((size_t)b * TSTEPS + TSTEPS - 1) * DD + 64 * oct + t] = hn_prev;
}

extern "C" void kernel_launch(void* const* d_in, const int* in_sizes, int n_in,
                              void* d_out, int out_size, void* d_ws, size_t ws_size,
                              hipStream_t stream) {
  (void)in_sizes; (void)n_in; (void)out_size; (void)ws_size;
  const float* x    = (const float*)d_in[0];
  const float* ctx  = (const float*)d_in[1];
  const float* W    = (const float*)d_in[2];
  const float* V    = (const float*)d_in[3];
  const float* U    = (const float*)d_in[4];
  const float* b    = (const float*)d_in[5];
  const float* Wh   = (const float*)d_in[6];
  const float* Wc   = (const float*)d_in[7];
  const float* batt = (const float*)d_in[8];
  const float* wprj = (const float*)d_in[9];

  // zero grid flags + rel + group flags
  hipMemsetAsync(d_ws, 0, (8192 + 256 + 8192) * sizeof(int), stream);

  hipLaunchKernelGGL(attn_lstm_persistent, dim3(GD), dim3(BD), 0, stream,
                     x, ctx, W, V, U, b, Wh, Wc, batt, wprj,
                     (float*)d_out, (float*)d_ws);
}

// Round 10
// 3930.903 us; speedup vs baseline: 1.0046x; 1.0046x over previous
//
#include <hip/hip_runtime.h>
#include <hip/hip_fp16.h>

#define GD 256   // 1 WG per CU, persistent
#define BD 1024  // 16 waves

constexpr int TSTEPS = 256;
constexpr int DD = 512;
constexpr int LC = 128;

// ---- ws float offsets ----
constexpr size_t OFF_FLAGS_F = 0;       // grid flags: 256 lines (stride 32 ints)
constexpr size_t OFF_REL_F   = 8192;    // 8 release lines
constexpr size_t OFF_GFLG_F  = 8448;    // group flags [32 b][8 oct][32 ints]
constexpr size_t OFF_SCP     = 16640;   // [32 b][8 oct][128 l] f32 score partials
constexpr size_t OFF_H16_F   = 49408;   // h16 base
// ---- h16-unit offsets ----
constexpr size_t HO_HX    = 0;          // [32 b][512] h (latest only)
constexpr size_t HO_ATT   = 16384;      // [4096 r][512] attc
constexpr size_t HO_U16   = 2113536;    // [8 oct][256 kp][256 cc] h2
constexpr size_t HO_WH16  = 3162112;    // [8 octa][256 kp][64 a] h2
constexpr size_t HO_CTXV  = 3424256;    // [32 b][8 oct][128 l][256 cc]
constexpr size_t HO_XW    = 11812864;   // [32 b][8 oct][256 st][256 cc]

typedef _Float16 h16;
typedef _Float16 h2  __attribute__((ext_vector_type(2)));
typedef _Float16 h8v __attribute__((ext_vector_type(8)));
union H8  { h8v v; h2 p[4]; };
union H2U { h2 h; unsigned u; };
union HSU { h16 h; unsigned short u; };

__device__ __forceinline__ float rcp_fast(float x) { return __builtin_amdgcn_rcpf(x); }
__device__ __forceinline__ float ftanh(float x) {
  float e = __expf(2.0f * x);
  return 1.0f - 2.0f * rcp_fast(e + 1.0f);
}
__device__ __forceinline__ float fsig(float x) { return rcp_fast(1.0f + __expf(-x)); }
__device__ __forceinline__ float fdot2(h2 a, h2 b, float c) {
  return __builtin_amdgcn_fdot2(a, b, c, false);
}

__device__ __forceinline__ float cloadf(const float* p) {
  return __hip_atomic_load(p, __ATOMIC_RELAXED, __HIP_MEMORY_SCOPE_AGENT);
}
__device__ __forceinline__ unsigned cloadu(const unsigned* p) {
  return __hip_atomic_load(p, __ATOMIC_RELAXED, __HIP_MEMORY_SCOPE_AGENT);
}
__device__ __forceinline__ void cstoref(float* p, float v) {
  __hip_atomic_store(p, v, __ATOMIC_RELAXED, __HIP_MEMORY_SCOPE_AGENT);
}
__device__ __forceinline__ void cstoreu(unsigned* p, unsigned v) {
  __hip_atomic_store(p, v, __ATOMIC_RELAXED, __HIP_MEMORY_SCOPE_AGENT);
}
__device__ __forceinline__ void cstoreu8(unsigned long long* p, unsigned long long v) {
  __hip_atomic_store(p, v, __ATOMIC_RELAXED, __HIP_MEMORY_SCOPE_AGENT);
}
__device__ __forceinline__ void cstores(h16* p, h16 v) {
  HSU s; s.h = v;
  __hip_atomic_store((unsigned short*)p, s.u, __ATOMIC_RELAXED,
                     __HIP_MEMORY_SCOPE_AGENT);
}

// grid barrier (setup only)
__device__ __forceinline__ void gsync(int* flags, int* rel, int w, int& gen) {
  __syncthreads();
  gen++;
  const int t = threadIdx.x;
  if (w == 0) {
    if (t < 64) {
      if (t == 0)
        __hip_atomic_store(flags, gen, __ATOMIC_RELAXED, __HIP_MEMORY_SCOPE_AGENT);
      for (;;) {
        int m = gen;
#pragma unroll
        for (int i = 0; i < 4; i++) {
          int v = __hip_atomic_load(flags + (t + i * 64) * 32,
                                    __ATOMIC_RELAXED, __HIP_MEMORY_SCOPE_AGENT);
          m = (v < m) ? v : m;
        }
        if (__all(m >= gen)) break;
      }
      if (t == 0) {
#pragma unroll
        for (int i = 0; i < 8; i++)
          __hip_atomic_store(rel + i * 32, gen, __ATOMIC_RELAXED,
                             __HIP_MEMORY_SCOPE_AGENT);
      }
    }
    asm volatile("" ::: "memory");
  } else {
    if (t == 0) {
      __hip_atomic_store(flags + w * 32, gen, __ATOMIC_RELAXED,
                         __HIP_MEMORY_SCOPE_AGENT);
      const int* r = rel + (w & 7) * 32;
      while (__hip_atomic_load(r, __ATOMIC_RELAXED, __HIP_MEMORY_SCOPE_AGENT) < gen)
        __builtin_amdgcn_s_sleep(1);
    }
    asm volatile("" ::: "memory");
  }
  __syncthreads();
}

// 8-WG (per-batch) group barrier: symmetric flag + poll
__device__ __forceinline__ void gbar8(int* gf, int oct, int& sg) {
  __syncthreads();
  sg++;
  const int t = threadIdx.x;
  if (t < 64) {
    if (t == 0)
      __hip_atomic_store(gf + oct * 32, sg, __ATOMIC_RELAXED,
                         __HIP_MEMORY_SCOPE_AGENT);
    for (;;) {
      int v = sg;
      if (t < 8)
        v = __hip_atomic_load(gf + t * 32, __ATOMIC_RELAXED,
                              __HIP_MEMORY_SCOPE_AGENT);
      if (__all(v >= sg)) break;
      __builtin_amdgcn_s_sleep(1);
    }
  }
  asm volatile("" ::: "memory");
  __syncthreads();
}

__global__ __launch_bounds__(BD)
__attribute__((amdgpu_waves_per_eu(4, 4)))
void attn_lstm_persistent(
    const float* __restrict__ x, const float* __restrict__ ctx,
    const float* __restrict__ W, const float* __restrict__ V,
    const float* __restrict__ U, const float* __restrict__ bias,
    const float* __restrict__ Wh, const float* __restrict__ Wc,
    const float* __restrict__ batt, const float* __restrict__ wprj,
    float* __restrict__ out, float* __restrict__ ws) {
  __shared__ __align__(16) unsigned char smem[46848];
  h16*   attcL = (h16*)smem;                   // [128 l][66] = 16896 B
  float* red   = (float*)(smem + 16896);       // 4096 f (P1: [4][256]; P2: [16][256])
  float* red2  = (float*)(smem + 33280);       // [16][64] f
  h2*    hLDS  = (h2*)(smem + 37376);          // 256 h2 = h[b]
  float* hUk   = (float*)(smem + 38400);       // 256
  float* spp   = (float*)(smem + 39424);       // 1024 (score-partial gather)
  float* sl    = (float*)(smem + 43520);       // 128 (exp scores)
  h2*    anL   = (h2*)(smem + 44032);          // 64 (fp16 alpha pairs)
  float* hattL = (float*)(smem + 44288);       // 64
  float* wpL   = (float*)(smem + 44544);       // 64
  float* biasS = (float*)(smem + 44800);       // 256
  float* pre   = (float*)(smem + 45824);       // 256

  const int w = blockIdx.x;
  const int t = threadIdx.x;
  const int b = w >> 3;    // batch owned by this group
  const int oct = w & 7;   // dim-slice [64*oct, 64*oct+64)

  int* flags = (int*)(ws + OFF_FLAGS_F);
  int* rel   = (int*)(ws + OFF_REL_F);
  int* gfl   = (int*)(ws + OFF_GFLG_F) + b * 256;
  float* scP = ws + OFF_SCP;
  h16* hb16  = (h16*)(ws + OFF_H16_F);
  h16* hX    = hb16 + HO_HX;
  h16* att16 = hb16 + HO_ATT;
  h16* ctxVp = hb16 + HO_CTXV;
  h16* xw16  = hb16 + HO_XW;

  int gen = 0, sg = 0;
  float c_reg = 0.f;       // t<64: cell state c[b][64*oct + t]
  float hn_prev = 0.f;     // t<64: h of previous step (deferred out-store)

  // ================= setup (verified packing, kept identical) =================
  {
    const int kp = w;
    {
      const float* r0p = U + (size_t)(2 * kp) * 2048;
      const float* r1p = r0p + 2048;
      const int col0 = 2 * t;
      float u00 = r0p[col0], u01 = r0p[col0 + 1];
      float u10 = r1p[col0], u11 = r1p[col0 + 1];
      int oc  = (col0 & 511) >> 6;
      int cc0 = ((col0 >> 9) << 6) | (col0 & 63);
      H2U p0; p0.h = h2{(h16)u00, (h16)u10};
      H2U p1; p1.h = h2{(h16)u01, (h16)u11};
      unsigned long long pk =
          (unsigned long long)p0.u | ((unsigned long long)p1.u << 32);
      cstoreu8((unsigned long long*)((h2*)(hb16 + HO_U16) +
                                     (size_t)oc * 65536 + (size_t)kp * 256 + cc0),
               pk);
    }
    if (t < 512) {
      float w0 = Wh[(size_t)(2 * kp) * DD + t];
      float w1 = Wh[(size_t)(2 * kp + 1) * DD + t];
      H2U pu; pu.h = h2{(h16)w0, (h16)w1};
      cstoreu((unsigned*)((h2*)(hb16 + HO_WH16) + (size_t)(t >> 6) * 16384 +
                          (size_t)kp * 64 + (t & 63)),
              pu.u);
    }
  }
  // attc16 = fp16(ctx @ Wc + b_att): 16 rows per WG
  {
    float* fbuf = (float*)smem;  // 32 KB staging (dead after gsync)
    const int r0 = w * 16;
#pragma unroll
    for (int i = 0; i < 2; i++) {
      int idx4 = i * BD + t;
      int row = idx4 >> 7, c4 = idx4 & 127;
      ((float4*)fbuf)[idx4] = ((const float4*)(ctx + (size_t)(r0 + row) * DD))[c4];
    }
    __syncthreads();
    const int a0 = t & 511, rh = t >> 9;
    float acc[8];
#pragma unroll
    for (int r = 0; r < 8; r++) acc[r] = 0.f;
    for (int cc = 0; cc < DD; cc++) {
      float wv = Wc[(size_t)cc * DD + a0];
#pragma unroll
      for (int r = 0; r < 8; r++)
        acc[r] += fbuf[(8 * rh + r) * DD + cc] * wv;
    }
    const float ba = batt[a0];
    for (int r = 0; r < 8; r++)
      cstores(att16 + (size_t)(r0 + 8 * rh + r) * DD + a0, (h16)(acc[r] + ba));
    __syncthreads();
  }
  // xw16 / ctxVp produced with setup-role (bS = w>>3, octS = w&7) — == (b, oct)
  {
    const int bS = w >> 3, octS = w & 7;
    h2* xstage = (h2*)smem;  // [32][256]
    for (int chk = 0; chk < 8; chk++) {
      const int st0 = chk * 32;
      {
        const int row = t >> 5, seg = t & 31;
        const float* src = x + ((size_t)bS * TSTEPS + st0 + row) * DD + seg * 16;
        h2* dst = xstage + row * 256 + seg * 8;
#pragma unroll
        for (int q = 0; q < 4; q++) {
          float4 v = *(const float4*)(src + 4 * q);
          dst[2 * q]     = h2{(h16)v.x, (h16)v.y};
          dst[2 * q + 1] = h2{(h16)v.z, (h16)v.w};
        }
      }
      __syncthreads();
      const int cc = t & 255, sq = t >> 8;
      const int col = ((cc >> 6) << 9) + 64 * octS + (cc & 63);
      float acc[8];
#pragma unroll
      for (int jj = 0; jj < 8; jj++) acc[jj] = 0.f;
#pragma unroll 2
      for (int kp = 0; kp < 256; kp++) {
        float w0 = W[(size_t)(2 * kp) * 2048 + col];
        float w1 = W[(size_t)(2 * kp + 1) * 2048 + col];
        h2 wp = h2{(h16)w0, (h16)w1};
#pragma unroll
        for (int jj = 0; jj < 8; jj++)
          acc[jj] = fdot2(xstage[(sq * 8 + jj) * 256 + kp], wp, acc[jj]);
      }
#pragma unroll
      for (int jj = 0; jj < 8; jj++)
        cstores(xw16 + (((size_t)(bS * 8 + octS) * 256) + st0 + sq * 8 + jj) * 256 + cc,
                (h16)acc[jj]);
      __syncthreads();
    }
    for (int chk = 0; chk < 4; chk++) {
      const int l0 = chk * 32;
      {
        const int row = t >> 5, seg = t & 31;
        const float* src = ctx + ((size_t)bS * LC + l0 + row) * DD + seg * 16;
        h2* dst = xstage + row * 256 + seg * 8;
#pragma unroll
        for (int q = 0; q < 4; q++) {
          float4 v = *(const float4*)(src + 4 * q);
          dst[2 * q]     = h2{(h16)v.x, (h16)v.y};
          dst[2 * q + 1] = h2{(h16)v.z, (h16)v.w};
        }
      }
      __syncthreads();
      const int cc = t & 255, lq = t >> 8;
      const int col = ((cc >> 6) << 9) + 64 * octS + (cc & 63);
      float acc[8];
#pragma unroll
      for (int jj = 0; jj < 8; jj++) acc[jj] = 0.f;
#pragma unroll 2
      for (int kp = 0; kp < 256; kp++) {
        float v0 = V[(size_t)(2 * kp) * 2048 + col];
        float v1 = V[(size_t)(2 * kp + 1) * 2048 + col];
        h2 vp = h2{(h16)v0, (h16)v1};
#pragma unroll
        for (int jj = 0; jj < 8; jj++)
          acc[jj] = fdot2(xstage[(lq * 8 + jj) * 256 + kp], vp, acc[jj]);
      }
#pragma unroll
      for (int jj = 0; jj < 8; jj++)
        cstores(ctxVp + (((size_t)(bS * 8 + octS) * 128) + l0 + lq * 8 + jj) * 256 + cc,
                (h16)acc[jj]);
      __syncthreads();
    }
  }
  gsync(flags, rel, w, gen);

  // ======== persistent operands: U -> 64 VGPR, ctxV -> 16 VGPR, attc -> LDS ====
  const int ccT = t & 255, kq = t >> 8;  // hU: packed col ccT, kp in [64kq, 64kq+64)
  h2 u[64], cvp01[8], cvp23[8];
  {
    const h2* Ub = (const h2*)(hb16 + HO_U16) + (size_t)oct * 65536 + ccT;
#pragma unroll
    for (int i = 0; i < 64; i++) u[i] = Ub[(size_t)(64 * kq + i) * 256];
  }
  {
    const int ccg = t & 31, lq = t >> 5;
    const h16* cvb = ctxVp + ((size_t)(b * 8 + oct) * 128) * 256 + ccg * 8;
    H8 p0, p1, p2, p3;
    p0.v = *(const h8v*)(cvb + (size_t)(4 * lq + 0) * 256);
    p1.v = *(const h8v*)(cvb + (size_t)(4 * lq + 1) * 256);
    p2.v = *(const h8v*)(cvb + (size_t)(4 * lq + 2) * 256);
    p3.v = *(const h8v*)(cvb + (size_t)(4 * lq + 3) * 256);
#pragma unroll
    for (int j8 = 0; j8 < 8; j8++) {
      cvp01[j8] = h2{p0.v[j8], p1.v[j8]};
      cvp23[j8] = h2{p2.v[j8], p3.v[j8]};
    }
  }
  {
    // attcL[l][66]: my batch's 64 a-cols (a = 64*oct + [0,64))
    const int l = t >> 3, as = t & 7;
    uint4 v = *(const uint4*)(att16 + (size_t)(b * LC + l) * DD + 64 * oct + 8 * as);
    unsigned* dp = (unsigned*)(attcL + l * 66 + 8 * as);
    dp[0] = v.x; dp[1] = v.y; dp[2] = v.z; dp[3] = v.w;
  }
  if (t < 64) wpL[t] = wprj[64 * oct + t];
  if (t < 256) biasS[t] = bias[(size_t)(t >> 6) * 512 + 64 * oct + (t & 63)];
  __syncthreads();

  const h2* WhB = (const h2*)(hb16 + HO_WH16) + (size_t)oct * 16384;

  // ========== recurrence: 2 phases, 2 group barriers/step ==========
  for (int step = 0; step < TSTEPS; step++) {
    float xwv = 0.f;

    // deferred out-store for previous step (ack drains under P1 compute)
    if (t < 64 && step > 0)
      out[((size_t)b * TSTEPS + step - 1) * DD + 64 * oct + t] = hn_prev;

    // ---- P1: h gather; hU (U regs, local); hatt (Wh L2); scores (local) ----
    {
      if (t < 256) {
        unsigned hv = 0;
        if (step > 0) hv = cloadu((const unsigned*)(hX + (size_t)b * DD + 2 * t));
        ((unsigned*)hLDS)[t] = hv;
      }
      __syncthreads();
      // hU partial: 64 fdot2, register U
      {
        float f0 = 0.f, f1 = 0.f;
        const int base = 64 * kq;
#pragma unroll
        for (int i = 0; i < 32; i++) f0 = fdot2(hLDS[base + i], u[i], f0);
#pragma unroll
        for (int i = 32; i < 64; i++) f1 = fdot2(hLDS[base + i], u[i], f1);
        red[kq * 256 + ccT] = f0 + f1;
      }
      // hatt partial: 16 fdot2, Wh streamed (64 KB, L2-resident, write-once)
      {
        const int aL = t & 63, ks = t >> 6;
        float g0 = 0.f;
#pragma unroll
        for (int i = 0; i < 16; i++)
          g0 = fdot2(hLDS[16 * ks + i], WhB[(size_t)(16 * ks + i) * 64 + aL], g0);
        red2[ks * 64 + aL] = g0;
      }
      // xw prefetch for this step (hides HBM latency under P1)
      if (t < 256)
        xwv = (float)xw16[(((size_t)(b * 8 + oct)) * 256 + step) * 256 + t];
      __syncthreads();
      if (t < 256) {
        hUk[t] = red[t] + red[256 + t] + red[512 + t] + red[768 + t];
      } else if (t < 320) {
        const int a = t - 256;
        float s = 0.f;
#pragma unroll
        for (int k = 0; k < 16; k++) s += red2[k * 64 + a];
        hattL[a] = s;
      }
      __syncthreads();
      // score partials over my 64 a-cols, all 128 l
      {
        const int l = t >> 3, as = t & 7;
        const h16* arow = attcL + l * 66 + 8 * as;
        float p = 0.f;
#pragma unroll
        for (int aa = 0; aa < 8; aa++)
          p += ftanh((float)arow[aa] + hattL[8 * as + aa]) * wpL[8 * as + aa];
        p += __shfl_xor(p, 1); p += __shfl_xor(p, 2); p += __shfl_xor(p, 4);
        if (as == 0)
          cstoref(scP + (size_t)b * 1024 + oct * 128 + l, p);
      }
    }
    gbar8(gfl, oct, sg);

    // ---- P2: sum 8 partials -> softmax (1 wave) -> PV (regs) -> gates -> h ----
    {
      spp[t] = cloadf(scP + (size_t)b * 1024 + t);  // [oct'=t>>7][l=t&127]
      __syncthreads();
      if (t < 64) {
        float s0 = 0.f, s1 = 0.f;
#pragma unroll
        for (int o = 0; o < 8; o++) {
          s0 += spp[o * 128 + t];
          s1 += spp[o * 128 + 64 + t];
        }
        float e0 = __expf(s0), e1 = __expf(s1);
        sl[t] = e0; sl[64 + t] = e1;
        float z = e0 + e1;
        z += __shfl_xor(z, 32); z += __shfl_xor(z, 16); z += __shfl_xor(z, 8);
        z += __shfl_xor(z, 4);  z += __shfl_xor(z, 2);  z += __shfl_xor(z, 1);
        float zi = rcp_fast(z);
        anL[t] = h2{(h16)(sl[2 * t] * zi), (h16)(sl[2 * t + 1] * zi)};
      }
      __syncthreads();
      {
        const int ccg = t & 31, lq = t >> 5, w16 = t >> 6;
        h2 a01 = anL[2 * lq], a23 = anL[2 * lq + 1];
        float acc8[8];
#pragma unroll
        for (int j8 = 0; j8 < 8; j8++)
          acc8[j8] = fdot2(a23, cvp23[j8], fdot2(a01, cvp01[j8], 0.f));
#pragma unroll
        for (int j8 = 0; j8 < 8; j8++) acc8[j8] += __shfl_xor(acc8[j8], 32);
        if ((t & 63) < 32) {
#pragma unroll
          for (int j8 = 0; j8 < 8; j8++)
            red[w16 * 256 + ccg * 8 + j8] = acc8[j8];
        }
      }
      __syncthreads();
      if (t < 256) {
        float pvs = 0.f;
#pragma unroll
        for (int k = 0; k < 16; k++) pvs += red[k * 256 + t];
        pre[t] = pvs + hUk[t] + xwv + biasS[t];  // pvs already normalized
      }
      __syncthreads();
      if (t < 64) {
        const int d = t;
        float pi = pre[d], pf = pre[64 + d], po = pre[128 + d], pg = pre[192 + d];
        float ig = fsig(pi), fg = fsig(pf), og = fsig(po), gg = ftanh(pg);
        float cn = fg * c_reg + ig * gg;
        c_reg = cn;
        float hn = og * ftanh(cn);
        hn_prev = hn;
        cstores(hX + (size_t)b * DD + 64 * oct + d, (h16)hn);
      }
    }
    gbar8(gfl, oct, sg);
  }
  // final out-store (step TSTEPS-1)
  if (t < 64)
    out[((size_t)b * TSTEPS + TSTEPS - 1) * DD + 64 * oct + t] = hn_prev;
}

extern "C" void kernel_launch(void* const* d_in, const int* in_sizes, int n_in,
                              void* d_out, int out_size, void* d_ws, size_t ws_size,
                              hipStream_t stream) {
  (void)in_sizes; (void)n_in; (void)out_size; (void)ws_size;
  const float* x    = (const float*)d_in[0];
  const float* ctx  = (const float*)d_in[1];
  const float* W    = (const float*)d_in[2];
  const float* V    = (const float*)d_in[3];
  const float* U    = (const float*)d_in[4];
  const float* b    = (const float*)d_in[5];
  const float* Wh   = (const float*)d_in[6];
  const float* Wc   = (const float*)d_in[7];
  const float* batt = (const float*)d_in[8];
  const float* wprj = (const float*)d_in[9];

  // zero grid flags + rel + group flags
  hipMemsetAsync(d_ws, 0, (8192 + 256 + 8192) * sizeof(int), stream);

  hipLaunchKernelGGL(attn_lstm_persistent, dim3(GD), dim3(BD), 0, stream,
                     x, ctx, W, V, U, b, Wh, Wc, batt, wprj,
                     (float*)d_out, (float*)d_ws);
}